// Round 7
// baseline (172.662 us; speedup 1.0000x reference)
//
#include <hip/hip_runtime.h>
#include <hip/hip_bf16.h>
#include <math.h>

#define L_TAU_C 0.8f

typedef _Float16 half2_t __attribute__((ext_vector_type(2)));

union U32H2 { unsigned int u; half2_t h; };
__device__ __forceinline__ half2_t h2(unsigned int v) { U32H2 x; x.u = v; return x.h; }

__device__ __forceinline__ float sigmoidf_(float x) {
    return 1.0f / (1.0f + __expf(-x));
}

// ---------------------------------------------------------------------------
// Kernel 1: transpose x [128][4096][20] f32 -> xT [128][20][4096] f16.
// ---------------------------------------------------------------------------
__global__ __launch_bounds__(256) void k_transpose16(const float* __restrict__ x,
                                                     _Float16* __restrict__ xT) {
    int gp = blockIdx.x * 256 + threadIdx.x;      // 0..524287
    int b = gp >> 12, p = gp & 4095;
    const float4* src = reinterpret_cast<const float4*>(x + (size_t)gp * 20);
    float v[20];
#pragma unroll
    for (int k = 0; k < 5; ++k) {
        float4 q = src[k];
        v[4 * k + 0] = q.x; v[4 * k + 1] = q.y; v[4 * k + 2] = q.z; v[4 * k + 3] = q.w;
    }
    _Float16* dst = xT + (size_t)b * 20 * 4096 + p;
#pragma unroll
    for (int t = 0; t < 20; ++t) dst[(size_t)t * 4096] = (_Float16)v[t];
}

// ---------------------------------------------------------------------------
// Kernel 2: fused conv + SNU(s1,y1) + maxpool + partial FC dot.
// Grid = 768 (b,ch) XCD-swizzled; block = 384 (6 waves), 378 active:
// thread = (pool row r 0..26, col group g 0..13) -> 2 conv rows x 4 cols
// (g=13 handles the last 2 cols, rest masked via w2r=0).
// LDS: single-copy x tile [64 rows][72 halfs] (stride 144 B = 36 dwords ->
// rows self-stagger by 4 banks: no XOR swizzle needed, ~uniform bank use).
// Window start half 4g -> ALL ds_read_b64 8B-aligned from ONE copy.
// Pad halfs 64..71 zeroed once (finite -> masked junk cols stay non-NaN).
// Conv weights: 100 f32 loaded uniformly ONCE, packed to 50 half2 u32,
// readfirstlane-pinned into SGPRs; v_dot2_f32_f16 reads them as the one
// allowed SGPR operand -> zero per-t weight traffic on any pipe.
// Double-buffered tile, one barrier per t; per-wave partials via parity-
// double-buffered LDS red[], folded by tid0 one iteration later.
// ---------------------------------------------------------------------------
__device__ __forceinline__ void put_unit(_Float16* buf, int e, uint4 v) {
    int R = e >> 3, h = e & 7;
    *reinterpret_cast<uint4*>(&buf[R * 72 + h * 8]) = v;
}

template<int XMODE>   // 1 = f16 transposed input, 0 = strided fallback
__global__ __launch_bounds__(384, 5) void k_conv_snu(
    const float* __restrict__ x,      // [128][4096][20]
    const _Float16* __restrict__ xT,  // [128][20][4096]
    const float* __restrict__ Wc,     // [6][1][10][10]
    const float* __restrict__ bc,     // [6]
    const float* __restrict__ W2,     // [4374][2]
    float* __restrict__ part)         // [20][128][6][2]
{
    __shared__ _Float16 xsh[2][64 * 72];   // 18.4 KB
    __shared__ float red[2][6][2];

    const int tid = threadIdx.x;
    const int bi = blockIdx.x;
    const int xcd = bi & 7, slot = bi >> 3;
    const int b = (slot / 6) * 8 + xcd;   // all 6 ch of b on same XCD
    const int ch = slot % 6;

    const bool active = tid < 378;
    const int r = tid / 14;           // pool row 0..26
    const int g = tid % 14;           // col group: conv cols 4g..4g+3
    const int row0 = 2 * r;

    // ---- weights -> SGPRs (one-time, uniform) ----
    const float* wb = Wc + ch * 100;
    unsigned int wsg[50];
#pragma unroll
    for (int i = 0; i < 50; ++i) {
        U32H2 pk;
        pk.h = half2_t{(_Float16)wb[2 * i], (_Float16)wb[2 * i + 1]};
        wsg[i] = (unsigned int)__builtin_amdgcn_readfirstlane((int)pk.u);
    }

    float s1[2][4], y1[2][4];
#pragma unroll
    for (int i = 0; i < 2; ++i)
#pragma unroll
        for (int j = 0; j < 4; ++j) { s1[i][j] = 0.f; y1[i][j] = 0.f; }

    const float bch = bc[ch];

    // FC weights for this thread's 2 pool cols (pc = 2g+k; pc>=27 masked 0)
    float w2r[2][2];
    w2r[0][0] = 0.f; w2r[0][1] = 0.f; w2r[1][0] = 0.f; w2r[1][1] = 0.f;
    if (active) {
#pragma unroll
        for (int k = 0; k < 2; ++k) {
            int pc = 2 * g + k;
            if (pc < 27) {
                int f0 = ch * 729 + r * 27 + pc;
                w2r[k][0] = W2[(size_t)f0 * 2 + 0];
                w2r[k][1] = W2[(size_t)f0 * 2 + 1];
            }
        }
    }

    // ---- zero pads (both buffers), stage t=0 ----
    if (tid < 64) {
        uint4 z = {0u, 0u, 0u, 0u};
        *reinterpret_cast<uint4*>(&xsh[0][tid * 72 + 64]) = z;
        *reinterpret_cast<uint4*>(&xsh[1][tid * 72 + 64]) = z;
    }
    const uint4* gsrc = reinterpret_cast<const uint4*>(xT + (size_t)b * 20 * 4096);
    if (XMODE == 1) {
        put_unit(xsh[0], tid, gsrc[tid]);
        if (tid < 128) put_unit(xsh[0], tid + 384, gsrc[tid + 384]);
    } else {
        const float* xb = x + (size_t)b * 4096 * 20;
#pragma unroll
        for (int k = 0; k < 12; ++k) {
            int p = tid + k * 384;                 // 0..4607
            int R = p / 72, c = p % 72;
            xsh[0][p] = (c < 64) ? (_Float16)xb[(size_t)(R * 64 + c) * 20] : (_Float16)0.f;
        }
    }
    __syncthreads();

    const int wave = tid >> 6;

    for (int t = 0; t < 20; ++t) {
        // prefetch next tile into regs (hidden under compute)
        uint4 pfa, pfb;
        if (XMODE == 1 && t < 19) {
            pfa = gsrc[(t + 1) * 512 + tid];
            if (tid < 128) pfb = gsrc[(t + 1) * 512 + tid + 384];
        }
        // fold previous iteration's per-wave partials (parity buffer)
        if (tid == 0 && t > 0) {
            float q0 = 0.f, q1 = 0.f;
#pragma unroll
            for (int wv = 0; wv < 6; ++wv) {
                q0 += red[(t - 1) & 1][wv][0];
                q1 += red[(t - 1) & 1][wv][1];
            }
            float* dst = part + ((size_t)(t - 1) * 128 + b) * 12 + ch * 2;
            dst[0] = q0; dst[1] = q1;
        }

        const _Float16* cur = xsh[t & 1];
        float p0 = 0.f, p1 = 0.f;
        if (active) {
            float c0[4] = {0.f, 0.f, 0.f, 0.f};
            float c1[4] = {0.f, 0.f, 0.f, 0.f};
            const _Float16* base = cur + row0 * 72 + 4 * g;

#pragma unroll
            for (int xr = 0; xr < 11; ++xr) {
                unsigned int s[8];
#pragma unroll
                for (int q = 0; q < 4; ++q) {
                    uint2 v = *reinterpret_cast<const uint2*>(base + xr * 72 + 4 * q);
                    s[2 * q] = v.x; s[2 * q + 1] = v.y;
                }
                unsigned int ss[6];
#pragma unroll
                for (int i = 0; i < 6; ++i)
                    ss[i] = (s[i] >> 16) | (s[i + 1] << 16);   // v_alignbit

                if (xr <= 9) {
#pragma unroll
                    for (int m = 0; m < 5; ++m) {
                        half2_t w = h2(wsg[xr * 5 + m]);
                        c0[0] = __builtin_amdgcn_fdot2(h2(s[m]),      w, c0[0], false);
                        c0[1] = __builtin_amdgcn_fdot2(h2(ss[m]),     w, c0[1], false);
                        c0[2] = __builtin_amdgcn_fdot2(h2(s[m + 1]),  w, c0[2], false);
                        c0[3] = __builtin_amdgcn_fdot2(h2(ss[m + 1]), w, c0[3], false);
                    }
                }
                if (xr >= 1) {
#pragma unroll
                    for (int m = 0; m < 5; ++m) {
                        half2_t w = h2(wsg[(xr - 1) * 5 + m]);
                        c1[0] = __builtin_amdgcn_fdot2(h2(s[m]),      w, c1[0], false);
                        c1[1] = __builtin_amdgcn_fdot2(h2(ss[m]),     w, c1[1], false);
                        c1[2] = __builtin_amdgcn_fdot2(h2(s[m + 1]),  w, c1[2], false);
                        c1[3] = __builtin_amdgcn_fdot2(h2(ss[m + 1]), w, c1[3], false);
                    }
                }
            }
            // SNU: s = relu(c + 0.8*s*(1-y)); y = sigmoid(s + bc)
#pragma unroll
            for (int j = 0; j < 4; ++j) {
                float sa = fmaxf(c0[j] + L_TAU_C * s1[0][j] * (1.f - y1[0][j]), 0.f);
                float sb = fmaxf(c1[j] + L_TAU_C * s1[1][j] * (1.f - y1[1][j]), 0.f);
                s1[0][j] = sa; s1[1][j] = sb;
                y1[0][j] = sigmoidf_(sa + bch);
                y1[1][j] = sigmoidf_(sb + bch);
            }
            // maxpool 2x2 + partial FC dot (2 pool cols)
            float h0 = fmaxf(fmaxf(y1[0][0], y1[0][1]), fmaxf(y1[1][0], y1[1][1]));
            float h1 = fmaxf(fmaxf(y1[0][2], y1[0][3]), fmaxf(y1[1][2], y1[1][3]));
            p0 = h0 * w2r[0][0] + h1 * w2r[1][0];
            p1 = h0 * w2r[0][1] + h1 * w2r[1][1];
        }
        // wave reduce -> parity red buffer
#pragma unroll
        for (int off = 32; off >= 1; off >>= 1) {
            p0 += __shfl_down(p0, off);
            p1 += __shfl_down(p1, off);
        }
        if ((tid & 63) == 0) {
            red[t & 1][wave][0] = p0;
            red[t & 1][wave][1] = p1;
        }
        // write next tile into the other buffer
        if (t < 19) {
            _Float16* nb = xsh[(t + 1) & 1];
            if (XMODE == 1) {
                put_unit(nb, tid, pfa);
                if (tid < 128) put_unit(nb, tid + 384, pfb);
            } else {
                const float* xb = x + (size_t)b * 4096 * 20;
#pragma unroll
                for (int k = 0; k < 12; ++k) {
                    int p = tid + k * 384;
                    int R = p / 72, c = p % 72;
                    if (c < 64) nb[p] = (_Float16)xb[(size_t)(R * 64 + c) * 20 + t + 1];
                }
            }
        }
        __syncthreads();
    }
    // epilogue: fold t=19 partials
    if (tid == 0) {
        float q0 = 0.f, q1 = 0.f;
#pragma unroll
        for (int wv = 0; wv < 6; ++wv) { q0 += red[1][wv][0]; q1 += red[1][wv][1]; }
        float* dst = part + ((size_t)19 * 128 + b) * 12 + ch * 2;
        dst[0] = q0; dst[1] = q1;
    }
}

// ---------------------------------------------------------------------------
// Kernel 3: s2/y2 recurrence, out_rec, m, loss, acc. One block, 128 threads.
// ---------------------------------------------------------------------------
__global__ __launch_bounds__(128) void k_final(const float* __restrict__ part,
                                               const void* __restrict__ yraw,
                                               const float* __restrict__ b2,
                                               float* __restrict__ out) {
    __shared__ float red[4];
    const int b = threadIdx.x;  // 0..127

    // labels may be int64 (reference) or int32: detect.
    const int* yi = (const int*)yraw;
    bool i64 = true;
    for (int k = 0; k < 64; ++k) {
        if (yi[2 * k + 1] != 0) { i64 = false; break; }
    }
    int lbl = i64 ? (int)((const long long*)yraw)[b] : yi[b];

    float b20 = b2[0], b21 = b2[1];
    float s20 = 0.f, s21 = 0.f, y20 = 0.f, y21 = 0.f, m0 = 0.f, m1 = 0.f;
    float* orec = out + 257 + b * 42;
    orec[0] = 0.f; orec[1] = 0.f;
    for (int t = 0; t < 20; ++t) {
        const float4* pp = reinterpret_cast<const float4*>(part + ((size_t)t * 128 + b) * 12);
        float4 a = pp[0], c = pp[1], d = pp[2];
        float sum0 = a.x + a.z + c.x + c.z + d.x + d.z;
        float sum1 = a.y + a.w + c.y + c.w + d.y + d.w;
        s20 = fmaxf(sum0 + L_TAU_C * s20 * (1.f - y20), 0.f);
        s21 = fmaxf(sum1 + L_TAU_C * s21 * (1.f - y21), 0.f);
        y20 = sigmoidf_(s20 + b20);
        y21 = sigmoidf_(s21 + b21);
        orec[(t + 1) * 2 + 0] = y20;
        orec[(t + 1) * 2 + 1] = y21;
        m0 += y20; m1 += y21;
    }
    m0 *= 0.05f; m1 *= 0.05f;
    out[1 + b * 2 + 0] = m0;
    out[1 + b * 2 + 1] = m1;

    float mx = fmaxf(m0, m1);
    float lse = mx + logf(expf(m0 - mx) + expf(m1 - mx));
    float lossc = -(((lbl != 0) ? m1 : m0) - lse);
    int pred = (m1 > m0) ? 1 : 0;
    float accc = (pred == lbl) ? 1.f : 0.f;
#pragma unroll
    for (int off = 32; off >= 1; off >>= 1) {
        lossc += __shfl_down(lossc, off);
        accc += __shfl_down(accc, off);
    }
    if ((b & 63) == 0) { red[(b >> 6) * 2] = lossc; red[(b >> 6) * 2 + 1] = accc; }
    __syncthreads();
    if (b == 0) {
        out[0] = (red[0] + red[2]) * (1.f / 128.f);
        out[5633] = (red[1] + red[3]) * (1.f / 128.f);
    }
}

extern "C" void kernel_launch(void* const* d_in, const int* in_sizes, int n_in,
                              void* d_out, int out_size, void* d_ws, size_t ws_size,
                              hipStream_t stream) {
    const float* x  = (const float*)d_in[0];
    const void*  y  = d_in[1];
    const float* Wc = (const float*)d_in[2];
    const float* bc = (const float*)d_in[3];
    const float* W2 = (const float*)d_in[4];
    const float* b2 = (const float*)d_in[5];
    float* out = (float*)d_out;

    const size_t xt_bytes = (size_t)128 * 20 * 4096 * 2;    // 20,971,520
    const size_t part_bytes = (size_t)20 * 128 * 6 * 2 * 4; // 245,760
    const int use16 = (ws_size >= xt_bytes + part_bytes) ? 1 : 0;

    _Float16* xT = (_Float16*)d_ws;
    float* part = use16 ? (float*)((char*)d_ws + xt_bytes) : (float*)d_ws;

    if (use16) {
        k_transpose16<<<2048, 256, 0, stream>>>(x, xT);
        k_conv_snu<1><<<768, 384, 0, stream>>>(x, xT, Wc, bc, W2, part);
    } else {
        k_conv_snu<0><<<768, 384, 0, stream>>>(x, (const _Float16*)d_ws, Wc, bc, W2, part);
    }
    k_final<<<1, 128, 0, stream>>>(part, y, b2, out);
}